// Round 1
// baseline (83.569 us; speedup 1.0000x reference)
//
#include <hip/hip_runtime.h>
#include <math.h>

static constexpr int NPOS = 32 * 56 * 56;   // 100352 spatial positions
static constexpr int CCH  = 256;            // channels
static constexpr double EPSV = 1e-6;

// ---------------------------------------------------------------------------
// Kernel 1: per-d statistics. Lane = d (0..63). Wave loads 4 coalesced 256B
// segments per position (r,i,j,k components of all 64 d's).
// S layout: [14][64] doubles: q=0..3 sums(r,i,j,k), q=4..13 products
// (rr, ri, rj, rk, ii, ij, ik, jj, jk, kk)
// ---------------------------------------------------------------------------
__global__ __launch_bounds__(256) void hbn_reduce(const float* __restrict__ x,
                                                  double* __restrict__ S) {
  const int tid  = threadIdx.x;
  const int lane = tid & 63;
  const int gw   = blockIdx.x * (blockDim.x >> 6) + (tid >> 6);
  const int nw   = gridDim.x * (blockDim.x >> 6);

  float s0=0.f, s1=0.f, s2=0.f, s3=0.f;
  float q0=0.f,q1=0.f,q2=0.f,q3=0.f,q4=0.f,q5=0.f,q6=0.f,q7=0.f,q8=0.f,q9=0.f;

  for (int p = gw * 2; p < NPOS; p += nw * 2) {
    const float* b = x + (size_t)p * CCH + lane;
    float r0 = b[0],   i0 = b[64],  j0 = b[128], k0 = b[192];
    float r1 = b[256], i1 = b[320], j1 = b[384], k1 = b[448];
    s0 += r0 + r1; s1 += i0 + i1; s2 += j0 + j1; s3 += k0 + k1;
    q0 = fmaf(r0,r0, fmaf(r1,r1, q0));
    q1 = fmaf(r0,i0, fmaf(r1,i1, q1));
    q2 = fmaf(r0,j0, fmaf(r1,j1, q2));
    q3 = fmaf(r0,k0, fmaf(r1,k1, q3));
    q4 = fmaf(i0,i0, fmaf(i1,i1, q4));
    q5 = fmaf(i0,j0, fmaf(i1,j1, q5));
    q6 = fmaf(i0,k0, fmaf(i1,k1, q6));
    q7 = fmaf(j0,j0, fmaf(j1,j1, q7));
    q8 = fmaf(j0,k0, fmaf(j1,k1, q8));
    q9 = fmaf(k0,k0, fmaf(k1,k1, q9));
  }

  __shared__ float red[14][256];
  red[0][tid]=s0;  red[1][tid]=s1;  red[2][tid]=s2;  red[3][tid]=s3;
  red[4][tid]=q0;  red[5][tid]=q1;  red[6][tid]=q2;  red[7][tid]=q3;
  red[8][tid]=q4;  red[9][tid]=q5;  red[10][tid]=q6; red[11][tid]=q7;
  red[12][tid]=q8; red[13][tid]=q9;
  __syncthreads();
  if (tid < 64) {
#pragma unroll
    for (int q = 0; q < 14; ++q) {
      double v = (double)red[q][tid] + (double)red[q][tid+64]
               + (double)red[q][tid+128] + (double)red[q][tid+192];
      unsafeAtomicAdd(&S[q*64 + tid], v);   // native global_atomic_add_f64
    }
  }
}

// ---------------------------------------------------------------------------
// Kernel 2: per-d 4x4 covariance -> V^{-1/2} via Jacobi (f64) -> fold with
// affine G and mean/beta into one 4x4 matrix M[d] + per-channel offset.
// 1 block x 64 threads; all loops fully unrolled -> register arrays.
// ---------------------------------------------------------------------------
__global__ void hbn_solve(const double* __restrict__ S,
                          const float* __restrict__ beta,
                          const float* __restrict__ grr, const float* __restrict__ gri,
                          const float* __restrict__ grj, const float* __restrict__ grk,
                          const float* __restrict__ gii, const float* __restrict__ gij,
                          const float* __restrict__ gik, const float* __restrict__ gjj,
                          const float* __restrict__ gjk, const float* __restrict__ gkk,
                          float* __restrict__ Mmat, float* __restrict__ offv) {
  const int d = threadIdx.x;   // 0..63
  const double invM = 1.0 / (double)NPOS;

  double mu[4];
  mu[0] = S[0*64+d]*invM; mu[1] = S[1*64+d]*invM;
  mu[2] = S[2*64+d]*invM; mu[3] = S[3*64+d]*invM;

  double A[4][4];
  A[0][0] = S[4*64+d]*invM  - mu[0]*mu[0] + EPSV;
  A[0][1] = A[1][0] = S[5*64+d]*invM  - mu[0]*mu[1];
  A[0][2] = A[2][0] = S[6*64+d]*invM  - mu[0]*mu[2];
  A[0][3] = A[3][0] = S[7*64+d]*invM  - mu[0]*mu[3];
  A[1][1] = S[8*64+d]*invM  - mu[1]*mu[1] + EPSV;
  A[1][2] = A[2][1] = S[9*64+d]*invM  - mu[1]*mu[2];
  A[1][3] = A[3][1] = S[10*64+d]*invM - mu[1]*mu[3];
  A[2][2] = S[11*64+d]*invM - mu[2]*mu[2] + EPSV;
  A[2][3] = A[3][2] = S[12*64+d]*invM - mu[2]*mu[3];
  A[3][3] = S[13*64+d]*invM - mu[3]*mu[3] + EPSV;

  double U[4][4] = {{1,0,0,0},{0,1,0,0},{0,0,1,0},{0,0,0,1}};

#pragma unroll 1
  for (int sweep = 0; sweep < 8; ++sweep) {
#pragma unroll
    for (int p = 0; p < 3; ++p) {
#pragma unroll
      for (int q = p + 1; q < 4; ++q) {
        double apq = A[p][q];
        if (fabs(apq) > 1e-300) {
          double theta = (A[q][q] - A[p][p]) / (2.0 * apq);
          double t = 1.0 / (fabs(theta) + sqrt(theta*theta + 1.0));
          if (theta < 0.0) t = -t;
          double c = 1.0 / sqrt(t*t + 1.0);
          double s = t * c;
#pragma unroll
          for (int r = 0; r < 4; ++r) {
            double arp = A[r][p], arq = A[r][q];
            A[r][p] = c*arp - s*arq;  A[r][q] = s*arp + c*arq;
          }
#pragma unroll
          for (int r = 0; r < 4; ++r) {
            double apr = A[p][r], aqr = A[q][r];
            A[p][r] = c*apr - s*aqr;  A[q][r] = s*apr + c*aqr;
          }
#pragma unroll
          for (int r = 0; r < 4; ++r) {
            double urp = U[r][p], urq = U[r][q];
            U[r][p] = c*urp - s*urq;  U[r][q] = s*urp + c*urq;
          }
        }
      }
    }
  }

  double wis[4];
#pragma unroll
  for (int b = 0; b < 4; ++b) {
    double w = A[b][b];
    if (w < 1e-12) w = 1e-12;
    wis[b] = 1.0 / sqrt(w);
  }

  // Wm = U diag(wis) U^T
  double Wm[4][4];
#pragma unroll
  for (int a = 0; a < 4; ++a)
#pragma unroll
    for (int cc = 0; cc < 4; ++cc) {
      double acc = 0.0;
#pragma unroll
      for (int b = 0; b < 4; ++b) acc += U[a][b] * wis[b] * U[cc][b];
      Wm[a][cc] = acc;
    }

  double G[4][4];
  G[0][0] = grr[d]; G[0][1] = G[1][0] = gri[d];
  G[0][2] = G[2][0] = grj[d]; G[0][3] = G[3][0] = grk[d];
  G[1][1] = gii[d]; G[1][2] = G[2][1] = gij[d];
  G[1][3] = G[3][1] = gik[d];
  G[2][2] = gjj[d]; G[2][3] = G[3][2] = gjk[d];
  G[3][3] = gkk[d];

  double M[4][4];
#pragma unroll
  for (int e = 0; e < 4; ++e)
#pragma unroll
    for (int cc = 0; cc < 4; ++cc) {
      double acc = 0.0;
#pragma unroll
      for (int b = 0; b < 4; ++b) acc += G[e][b] * Wm[b][cc];
      M[e][cc] = acc;
      Mmat[d*16 + e*4 + cc] = (float)acc;
    }

  // off[e] = beta - M*mean  (folds centering + beta into the affine)
#pragma unroll
  for (int e = 0; e < 4; ++e) {
    double acc = (double)beta[e*64 + d];
#pragma unroll
    for (int cc = 0; cc < 4; ++cc) acc -= M[e][cc] * mu[cc];
    offv[e*64 + d] = (float)acc;
  }
}

// ---------------------------------------------------------------------------
// Kernel 3: y = ELU(M[d] * x_rijk + off). Lane = d; 4 coalesced segments
// in, 4 out, unroll 2 positions.
// ---------------------------------------------------------------------------
__global__ __launch_bounds__(256) void hbn_apply(const float* __restrict__ x,
                                                 const float* __restrict__ Mmat,
                                                 const float* __restrict__ offv,
                                                 float* __restrict__ out) {
  const int tid  = threadIdx.x;
  const int lane = tid & 63;
  const int gw   = blockIdx.x * (blockDim.x >> 6) + (tid >> 6);
  const int nw   = gridDim.x * (blockDim.x >> 6);

  float m0  = Mmat[lane*16+0],  m1  = Mmat[lane*16+1],  m2  = Mmat[lane*16+2],  m3  = Mmat[lane*16+3];
  float m4  = Mmat[lane*16+4],  m5  = Mmat[lane*16+5],  m6  = Mmat[lane*16+6],  m7  = Mmat[lane*16+7];
  float m8  = Mmat[lane*16+8],  m9  = Mmat[lane*16+9],  m10 = Mmat[lane*16+10], m11 = Mmat[lane*16+11];
  float m12 = Mmat[lane*16+12], m13 = Mmat[lane*16+13], m14 = Mmat[lane*16+14], m15 = Mmat[lane*16+15];
  const float o0 = offv[lane], o1 = offv[64+lane], o2 = offv[128+lane], o3 = offv[192+lane];

  for (int p = gw * 2; p < NPOS; p += nw * 2) {
    const float* b = x + (size_t)p * CCH + lane;
    float r0 = b[0],   i0 = b[64],  j0 = b[128], k0 = b[192];
    float r1 = b[256], i1 = b[320], j1 = b[384], k1 = b[448];

    float ya0 = fmaf(m0, r0, fmaf(m1, i0, fmaf(m2, j0, fmaf(m3, k0, o0))));
    float ya1 = fmaf(m4, r0, fmaf(m5, i0, fmaf(m6, j0, fmaf(m7, k0, o1))));
    float ya2 = fmaf(m8, r0, fmaf(m9, i0, fmaf(m10,j0, fmaf(m11,k0, o2))));
    float ya3 = fmaf(m12,r0, fmaf(m13,i0, fmaf(m14,j0, fmaf(m15,k0, o3))));
    float yb0 = fmaf(m0, r1, fmaf(m1, i1, fmaf(m2, j1, fmaf(m3, k1, o0))));
    float yb1 = fmaf(m4, r1, fmaf(m5, i1, fmaf(m6, j1, fmaf(m7, k1, o1))));
    float yb2 = fmaf(m8, r1, fmaf(m9, i1, fmaf(m10,j1, fmaf(m11,k1, o2))));
    float yb3 = fmaf(m12,r1, fmaf(m13,i1, fmaf(m14,j1, fmaf(m15,k1, o3))));

    ya0 = ya0 > 0.f ? ya0 : (__expf(ya0) - 1.f);
    ya1 = ya1 > 0.f ? ya1 : (__expf(ya1) - 1.f);
    ya2 = ya2 > 0.f ? ya2 : (__expf(ya2) - 1.f);
    ya3 = ya3 > 0.f ? ya3 : (__expf(ya3) - 1.f);
    yb0 = yb0 > 0.f ? yb0 : (__expf(yb0) - 1.f);
    yb1 = yb1 > 0.f ? yb1 : (__expf(yb1) - 1.f);
    yb2 = yb2 > 0.f ? yb2 : (__expf(yb2) - 1.f);
    yb3 = yb3 > 0.f ? yb3 : (__expf(yb3) - 1.f);

    float* ob = out + (size_t)p * CCH + lane;
    ob[0]   = ya0; ob[64]  = ya1; ob[128] = ya2; ob[192] = ya3;
    ob[256] = yb0; ob[320] = yb1; ob[384] = yb2; ob[448] = yb3;
  }
}

extern "C" void kernel_launch(void* const* d_in, const int* in_sizes, int n_in,
                              void* d_out, int out_size, void* d_ws, size_t ws_size,
                              hipStream_t stream) {
  (void)in_sizes; (void)n_in; (void)out_size; (void)ws_size;
  const float* x    = (const float*)d_in[0];
  const float* beta = (const float*)d_in[1];
  const float* grr  = (const float*)d_in[2];
  const float* gri  = (const float*)d_in[3];
  const float* grj  = (const float*)d_in[4];
  const float* grk  = (const float*)d_in[5];
  const float* gii  = (const float*)d_in[6];
  const float* gij  = (const float*)d_in[7];
  const float* gik  = (const float*)d_in[8];
  const float* gjj  = (const float*)d_in[9];
  const float* gjk  = (const float*)d_in[10];
  const float* gkk  = (const float*)d_in[11];
  float* out = (float*)d_out;

  double* S   = (double*)d_ws;                                        // 14*64 f64 = 7168 B
  float* Mmat = (float*)((char*)d_ws + 14*64*sizeof(double));         // 64*16 f32 = 4096 B
  float* offv = (float*)((char*)d_ws + 14*64*sizeof(double) + 64*16*sizeof(float)); // 256 f32

  // ws is NOT re-poisoned between replays: zero the accumulators every call.
  hipMemsetAsync(d_ws, 0, 14*64*sizeof(double), stream);
  hbn_reduce<<<512, 256, 0, stream>>>(x, S);
  hbn_solve<<<1, 64, 0, stream>>>(S, beta, grr, gri, grj, grk,
                                  gii, gij, gik, gjj, gjk, gkk, Mmat, offv);
  hbn_apply<<<1024, 256, 0, stream>>>(x, Mmat, offv, out);
}